// Round 1
// baseline (230.157 us; speedup 1.0000x reference)
//
#include <hip/hip_runtime.h>

typedef __attribute__((ext_vector_type(8))) short short8;
typedef __attribute__((ext_vector_type(4))) float f32x4;

#define GLDS16(gp, lp)                                                                     \
  __builtin_amdgcn_global_load_lds(                                                        \
      (const __attribute__((address_space(1))) unsigned int*)(gp),                         \
      (__attribute__((address_space(3))) unsigned int*)(lp), 16, 0, 0)

__device__ __forceinline__ unsigned short f2bf(float f) {
  unsigned u = __float_as_uint(f);
  u += 0x7FFFu + ((u >> 16) & 1u);
  return (unsigned short)(u >> 16);
}
__device__ __forceinline__ float bf2f(unsigned short h) {
  return __uint_as_float(((unsigned)h) << 16);
}

// ---------------------------------------------------------------------------
// Kernel 1: prep — x->bf16, W_qkv -> [n][k] bf16, W_out -> hi/lo [n][k] bf16,
// jmask[b][j] = 1.0 if column j is masked ((np==0)||(bert==1)) else 0.0
// ---------------------------------------------------------------------------
#define R1 524288            // x: 2M elems / 4 per thread
#define R2 786432            // wqkvT elems
#define R3 262144            // wout elems
#define R4 4096              // jmask elems

__global__ __launch_bounds__(256) void prep_kernel(
    const float* __restrict__ x, const int* __restrict__ mnp, const int* __restrict__ mbert,
    const float* __restrict__ wqkv, const float* __restrict__ wout,
    unsigned short* __restrict__ xb, unsigned short* __restrict__ wqkvT,
    unsigned short* __restrict__ whiT, unsigned short* __restrict__ wloT,
    float* __restrict__ jmask) {
  int tid = blockIdx.x * 256 + threadIdx.x;
  if (tid < R1) {
    float4 v = *(const float4*)(x + tid * 4);
    ushort4 o;
    o.x = f2bf(v.x); o.y = f2bf(v.y); o.z = f2bf(v.z); o.w = f2bf(v.w);
    *(ushort4*)(xb + tid * 4) = o;
  } else if (tid < R1 + R2) {
    int o = tid - R1;               // linear over [512][1536], coalesced read
    int kk = o / 1536, n = o - kk * 1536;
    wqkvT[n * 512 + kk] = f2bf(wqkv[o]);
  } else if (tid < R1 + R2 + R3) {
    int o = tid - (R1 + R2);        // linear over [512][512]
    int kk = o >> 9, n = o & 511;
    float w = wout[o];
    unsigned short hi = f2bf(w);
    whiT[n * 512 + kk] = hi;
    wloT[n * 512 + kk] = f2bf(w - bf2f(hi));
  } else {
    int o = tid - (R1 + R2 + R3);
    jmask[o] = (mnp[o] == 0 || mbert[o] == 1) ? 1.0f : 0.0f;
  }
}

// ---------------------------------------------------------------------------
// Kernel 2: QKV GEMM. C[4096][1536] = xb[4096][512] @ Wqkv, B given as Bt[n][k].
// 64x128 tile, 4 waves (each 64 rows x 32 cols), BK=64, global_load_lds + XOR
// swizzle (both-sides). Epilogue scatters into q (x0.125), k ([b,h,n,d]) and
// vT ([b,h,d,n]) bf16.
// ---------------------------------------------------------------------------
__global__ __launch_bounds__(256) void qkv_gemm(
    const unsigned short* __restrict__ A, const unsigned short* __restrict__ Bt,
    unsigned short* __restrict__ qb, unsigned short* __restrict__ kb,
    unsigned short* __restrict__ vtb) {
  __shared__ __attribute__((aligned(16))) unsigned short lA[64 * 64];
  __shared__ __attribute__((aligned(16))) unsigned short lB[128 * 64];
  const int lane = threadIdx.x & 63, wid = threadIdx.x >> 6;
  const int l15 = lane & 15, lg = lane >> 4;
  const int row0 = blockIdx.x * 64;
  const int col0 = blockIdx.y * 128;
  const int srow = lane >> 3;              // row within 8-row chunk
  const int gslot = (lane & 7) ^ srow;     // pre-swizzled global 16B-slot
  f32x4 acc[4][2] = {};

  for (int ks = 0; ks < 8; ++ks) {
    const int k0 = ks * 64;
    __syncthreads();
#pragma unroll
    for (int i = 0; i < 2; ++i) {
      int c = wid * 2 + i;
      GLDS16(A + (row0 + c * 8 + srow) * 512 + k0 + gslot * 8, lA + c * 512);
    }
#pragma unroll
    for (int i = 0; i < 4; ++i) {
      int c = wid * 4 + i;
      GLDS16(Bt + (col0 + c * 8 + srow) * 512 + k0 + gslot * 8, lB + c * 512);
    }
    __syncthreads();
#pragma unroll
    for (int ksub = 0; ksub < 2; ++ksub) {
      short8 af[4], bfr[2];
#pragma unroll
      for (int m = 0; m < 4; ++m) {
        int row = m * 16 + l15;
        int slot = (ksub * 4 + lg) ^ (row & 7);
        af[m] = *(const short8*)(lA + row * 64 + slot * 8);
      }
#pragma unroll
      for (int n = 0; n < 2; ++n) {
        int row = wid * 32 + n * 16 + l15;
        int slot = (ksub * 4 + lg) ^ (row & 7);
        bfr[n] = *(const short8*)(lB + row * 64 + slot * 8);
      }
#pragma unroll
      for (int m = 0; m < 4; ++m)
#pragma unroll
        for (int n = 0; n < 2; ++n)
          acc[m][n] = __builtin_amdgcn_mfma_f32_16x16x32_bf16(af[m], bfr[n], acc[m][n], 0, 0, 0);
    }
  }
#pragma unroll
  for (int m = 0; m < 4; ++m) {
#pragma unroll
    for (int n = 0; n < 2; ++n) {
      int col = col0 + wid * 32 + n * 16 + l15;     // 0..1535
      int which = col >> 9, hh = (col >> 6) & 7, d = col & 63;
#pragma unroll
      for (int r = 0; r < 4; ++r) {
        int grow = row0 + m * 16 + lg * 4 + r;      // 0..4095
        int b = grow >> 11, np = grow & 2047;
        float v = acc[m][n][r];
        if (which == 0)
          qb[((b * 8 + hh) * 2048 + np) * 64 + d] = f2bf(v * 0.125f);  // exact pow2 scale
        else if (which == 1)
          kb[((b * 8 + hh) * 2048 + np) * 64 + d] = f2bf(v);
        else
          vtb[((b * 8 + hh) * 64 + d) * 2048 + np] = f2bf(v);
      }
    }
  }
}

// ---------------------------------------------------------------------------
// Kernel 3: flash attention. Grid (16 heads, 32 row-blocks of 64), 4 waves.
// Wave owns 16 q-rows; j-tiles of 64; online softmax; P transposed to A-frag
// layout through a per-wave LDS buffer. Output written as hi/lo bf16 pair.
// ---------------------------------------------------------------------------
__global__ __launch_bounds__(256) void attn_kernel(
    const unsigned short* __restrict__ qg, const unsigned short* __restrict__ kg,
    const unsigned short* __restrict__ vtg, const int* __restrict__ mnp,
    const float* __restrict__ jmask,
    unsigned short* __restrict__ ahi, unsigned short* __restrict__ alo) {
  __shared__ __attribute__((aligned(16))) unsigned short Plds[4][16 * 72];
  const int lane = threadIdx.x & 63, wid = threadIdx.x >> 6;
  const int l15 = lane & 15, lg = lane >> 4;
  const int bh = blockIdx.x, b = bh >> 3, h = bh & 7;
  const int q0 = blockIdx.y * 64 + wid * 16;
  const unsigned short* Q = qg + bh * (2048 * 64);
  const unsigned short* K = kg + bh * (2048 * 64);
  const unsigned short* VT = vtg + bh * (64 * 2048);

  short8 qf[2];
#pragma unroll
  for (int s = 0; s < 2; ++s)
    qf[s] = *(const short8*)(Q + (q0 + l15) * 64 + s * 32 + lg * 8);

  float rowbad[4];
#pragma unroll
  for (int r = 0; r < 4; ++r)
    rowbad[r] = (mnp[b * 2048 + q0 + lg * 4 + r] == 0) ? 1.0f : 0.0f;

  float mrun[4], lrun[4];
  f32x4 accO[4] = {};
#pragma unroll
  for (int r = 0; r < 4; ++r) { mrun[r] = -1e30f; lrun[r] = 0.f; }

  unsigned short* Pl = &Plds[wid][0];

  for (int j0 = 0; j0 < 2048; j0 += 64) {
    float jm[4];
    short8 kf[4][2];
#pragma unroll
    for (int t = 0; t < 4; ++t) {
      jm[t] = jmask[b * 2048 + j0 + t * 16 + l15];
#pragma unroll
      for (int s = 0; s < 2; ++s)
        kf[t][s] = *(const short8*)(K + (j0 + t * 16 + l15) * 64 + s * 32 + lg * 8);
    }
    short8 vf[4][2];
#pragma unroll
    for (int dt = 0; dt < 4; ++dt)
#pragma unroll
      for (int c = 0; c < 2; ++c)
        vf[dt][c] = *(const short8*)(VT + (dt * 16 + l15) * 2048 + j0 + c * 32 + lg * 8);

    f32x4 sacc[4] = {};
#pragma unroll
    for (int t = 0; t < 4; ++t)
#pragma unroll
      for (int s = 0; s < 2; ++s)
        sacc[t] = __builtin_amdgcn_mfma_f32_16x16x32_bf16(qf[s], kf[t][s], sacc[t], 0, 0, 0);

    // mask + online softmax (rows live in 16-lane groups; shfl_xor<16 stays in group)
    float p[4][4], tmax[4];
#pragma unroll
    for (int r = 0; r < 4; ++r) tmax[r] = -1e30f;
#pragma unroll
    for (int t = 0; t < 4; ++t)
#pragma unroll
      for (int r = 0; r < 4; ++r) {
        float sv = sacc[t][r];
        sv = (rowbad[r] + jm[t] > 0.f) ? -1000.0f : sv;
        p[t][r] = sv;
        tmax[r] = fmaxf(tmax[r], sv);
      }
#pragma unroll
    for (int r = 0; r < 4; ++r) {
#pragma unroll
      for (int off = 1; off < 16; off <<= 1)
        tmax[r] = fmaxf(tmax[r], __shfl_xor(tmax[r], off));
    }
    float psum[4];
#pragma unroll
    for (int r = 0; r < 4; ++r) {
      float mnew = fmaxf(mrun[r], tmax[r]);
      float scl = __expf(mrun[r] - mnew);
      mrun[r] = mnew;
      lrun[r] *= scl;
      psum[r] = 0.f;
#pragma unroll
      for (int dt = 0; dt < 4; ++dt) accO[dt][r] *= scl;
    }
#pragma unroll
    for (int t = 0; t < 4; ++t)
#pragma unroll
      for (int r = 0; r < 4; ++r) {
        float e = __expf(p[t][r] - mrun[r]);
        p[t][r] = e;
        psum[r] += e;
      }
#pragma unroll
    for (int r = 0; r < 4; ++r) {
#pragma unroll
      for (int off = 1; off < 16; off <<= 1)
        psum[r] += __shfl_xor(psum[r], off);
      lrun[r] += psum[r];
    }
    // P -> A-fragment layout via wave-private LDS (wave-synchronous, no barrier)
#pragma unroll
    for (int t = 0; t < 4; ++t)
#pragma unroll
      for (int r = 0; r < 4; ++r)
        Pl[(lg * 4 + r) * 72 + t * 16 + l15] = f2bf(p[t][r]);
    short8 pa[2];
#pragma unroll
    for (int c = 0; c < 2; ++c)
      pa[c] = *(const short8*)(Pl + l15 * 72 + c * 32 + lg * 8);
#pragma unroll
    for (int dt = 0; dt < 4; ++dt)
#pragma unroll
      for (int c = 0; c < 2; ++c)
        accO[dt] = __builtin_amdgcn_mfma_f32_16x16x32_bf16(pa[c], vf[dt][c], accO[dt], 0, 0, 0);
  }
  // epilogue: normalize, split hi/lo bf16
#pragma unroll
  for (int dt = 0; dt < 4; ++dt) {
#pragma unroll
    for (int r = 0; r < 4; ++r) {
      float val = accO[dt][r] / lrun[r];
      int row = q0 + lg * 4 + r;
      int col = h * 64 + dt * 16 + l15;
      unsigned short hi = f2bf(val);
      float lo = val - bf2f(hi);
      ahi[(b * 2048 + row) * 512 + col] = hi;
      alo[(b * 2048 + row) * 512 + col] = f2bf(lo);
    }
  }
}

// ---------------------------------------------------------------------------
// Kernel 4: out-proj split-bf16 GEMM. Virtual K = 3*512: seg0 Ahi*Whi,
// seg1 Alo*Whi, seg2 Ahi*Wlo. 64x128 tile, same structure as qkv_gemm.
// ---------------------------------------------------------------------------
__global__ __launch_bounds__(256) void outproj_gemm(
    const unsigned short* __restrict__ Ahi, const unsigned short* __restrict__ Alo,
    const unsigned short* __restrict__ WhiT, const unsigned short* __restrict__ WloT,
    const float* __restrict__ bias, float* __restrict__ out) {
  __shared__ __attribute__((aligned(16))) unsigned short lA[64 * 64];
  __shared__ __attribute__((aligned(16))) unsigned short lB[128 * 64];
  const int lane = threadIdx.x & 63, wid = threadIdx.x >> 6;
  const int l15 = lane & 15, lg = lane >> 4;
  const int row0 = blockIdx.x * 64;
  const int col0 = blockIdx.y * 128;
  const int srow = lane >> 3;
  const int gslot = (lane & 7) ^ srow;
  f32x4 acc[4][2] = {};

  for (int ks = 0; ks < 24; ++ks) {
    const int seg = ks >> 3;
    const int k0 = (ks & 7) * 64;
    const unsigned short* Asrc = (seg == 1) ? Alo : Ahi;
    const unsigned short* Bsrc = (seg == 2) ? WloT : WhiT;
    __syncthreads();
#pragma unroll
    for (int i = 0; i < 2; ++i) {
      int c = wid * 2 + i;
      GLDS16(Asrc + (row0 + c * 8 + srow) * 512 + k0 + gslot * 8, lA + c * 512);
    }
#pragma unroll
    for (int i = 0; i < 4; ++i) {
      int c = wid * 4 + i;
      GLDS16(Bsrc + (col0 + c * 8 + srow) * 512 + k0 + gslot * 8, lB + c * 512);
    }
    __syncthreads();
#pragma unroll
    for (int ksub = 0; ksub < 2; ++ksub) {
      short8 af[4], bfr[2];
#pragma unroll
      for (int m = 0; m < 4; ++m) {
        int row = m * 16 + l15;
        int slot = (ksub * 4 + lg) ^ (row & 7);
        af[m] = *(const short8*)(lA + row * 64 + slot * 8);
      }
#pragma unroll
      for (int n = 0; n < 2; ++n) {
        int row = wid * 32 + n * 16 + l15;
        int slot = (ksub * 4 + lg) ^ (row & 7);
        bfr[n] = *(const short8*)(lB + row * 64 + slot * 8);
      }
#pragma unroll
      for (int m = 0; m < 4; ++m)
#pragma unroll
        for (int n = 0; n < 2; ++n)
          acc[m][n] = __builtin_amdgcn_mfma_f32_16x16x32_bf16(af[m], bfr[n], acc[m][n], 0, 0, 0);
    }
  }
#pragma unroll
  for (int m = 0; m < 4; ++m) {
#pragma unroll
    for (int n = 0; n < 2; ++n) {
      int col = col0 + wid * 32 + n * 16 + l15;
      float bb = bias[col];
#pragma unroll
      for (int r = 0; r < 4; ++r) {
        int grow = row0 + m * 16 + lg * 4 + r;
        out[grow * 512 + col] = acc[m][n][r] + bb;
      }
    }
  }
}

// ---------------------------------------------------------------------------
extern "C" void kernel_launch(void* const* d_in, const int* in_sizes, int n_in,
                              void* d_out, int out_size, void* d_ws, size_t ws_size,
                              hipStream_t stream) {
  (void)in_sizes; (void)n_in; (void)out_size; (void)ws_size;
  const float* x = (const float*)d_in[0];
  const int* mnp = (const int*)d_in[1];
  const int* mbert = (const int*)d_in[2];
  const float* wqkv = (const float*)d_in[3];
  const float* wout = (const float*)d_in[4];
  const float* bout = (const float*)d_in[5];
  float* out = (float*)d_out;

  char* ws = (char*)d_ws;
  size_t off = 0;
  auto alloc = [&](size_t bytes) {
    void* p = ws + off;
    off += (bytes + 255) & ~(size_t)255;
    return p;
  };
  unsigned short* xb    = (unsigned short*)alloc(2097152 * 2);  // x bf16 [4096][512]
  unsigned short* wqkvT = (unsigned short*)alloc(786432 * 2);   // [1536][512]
  unsigned short* qb    = (unsigned short*)alloc(2097152 * 2);  // [b,h,n,d]
  unsigned short* kb    = (unsigned short*)alloc(2097152 * 2);  // [b,h,n,d]
  unsigned short* vtb   = (unsigned short*)alloc(2097152 * 2);  // [b,h,d,n]
  unsigned short* ahi   = (unsigned short*)alloc(2097152 * 2);  // attn out hi [4096][512]
  unsigned short* alo   = (unsigned short*)alloc(2097152 * 2);  // attn out lo
  unsigned short* whiT  = (unsigned short*)alloc(262144 * 2);   // [512][512] n-major
  unsigned short* wloT  = (unsigned short*)alloc(262144 * 2);
  float* jmask          = (float*)alloc(4096 * 4);

  prep_kernel<<<6160, 256, 0, stream>>>(x, mnp, mbert, wqkv, wout, xb, wqkvT, whiT, wloT, jmask);
  qkv_gemm<<<dim3(64, 12), 256, 0, stream>>>(xb, wqkvT, qb, kb, vtb);
  attn_kernel<<<dim3(16, 32), 256, 0, stream>>>(qb, kb, vtb, mnp, jmask, ahi, alo);
  outproj_gemm<<<dim3(64, 4), 256, 0, stream>>>(ahi, alo, whiT, wloT, bout, out);
}